// Round 2
// baseline (411.582 us; speedup 1.0000x reference)
//
#include <hip/hip_runtime.h>
#include <hip/hip_bf16.h>

#define EMB   1024
#define SEQ   2048
#define BATCH 4
#define NH    16
#define DHEAD 64
#define MROWS (BATCH*SEQ)   // 8192

typedef float f32x4  __attribute__((ext_vector_type(4)));
typedef float f32x16 __attribute__((ext_vector_type(16)));
typedef short s16x8  __attribute__((ext_vector_type(8)));

__device__ __forceinline__ f32x4 mfma16(s16x8 a, s16x8 b, f32x4 c) {
    return __builtin_amdgcn_mfma_f32_16x16x32_bf16(a, b, c, 0, 0, 0);
}
__device__ __forceinline__ f32x16 mfma32(s16x8 a, s16x8 b, f32x16 c) {
    return __builtin_amdgcn_mfma_f32_32x32x16_bf16(a, b, c, 0, 0, 0);
}

__device__ __forceinline__ unsigned short f2bf(float f) {
    __hip_bfloat16 h = __float2bfloat16(f);
    return __builtin_bit_cast(unsigned short, h);
}

__device__ __forceinline__ unsigned cvtpk(float lo, float hi) {
    unsigned r;
    asm("v_cvt_pk_bf16_f32 %0, %1, %2" : "=v"(r) : "v"(lo), "v"(hi));
    return r;
}

// v_permlane32_swap_b32: new_a.hi_lanes = old_b.lo_lanes, new_b.lo_lanes = old_a.hi_lanes
__device__ __forceinline__ void plane_swap(unsigned &a, unsigned &b) {
    asm("v_permlane32_swap_b32 %0, %1" : "+v"(a), "+v"(b));
}

__device__ __forceinline__ s16x8 frag4(unsigned a, unsigned b, unsigned c, unsigned d) {
    union { unsigned u[4]; s16x8 f; } x;
    x.u[0] = a; x.u[1] = b; x.u[2] = c; x.u[3] = d;
    return x.f;
}

// ---------------- fp32 -> bf16 conversion (vectorized) ----------------
__global__ void cvt_bf16(const float* __restrict__ in, unsigned short* __restrict__ out, int n4) {
    int i = blockIdx.x * blockDim.x + threadIdx.x;
    if (i >= n4) return;
    float4 v = reinterpret_cast<const float4*>(in)[i];
    ushort4 o;
    o.x = f2bf(v.x); o.y = f2bf(v.y); o.z = f2bf(v.z); o.w = f2bf(v.w);
    reinterpret_cast<ushort4*>(out)[i] = o;
}

// ---------------- bf16 GEMM: C[M,N] = A[M,K] * B[N,K]^T + bias ----------------
// EPI==0: bf16 head-split [B,H,S,Dh], value scaled by oscale.
// EPI==1: fp32 row-major + bias.
// EPI==2: bf16 transposed head-split [B,H,Dh,S] (for V^T).
#define GLDS(g, s) __builtin_amdgcn_global_load_lds((const __attribute__((address_space(1))) void*)(g), \
                       (__attribute__((address_space(3))) void*)(s), 16, 0, 0)

template<int EPI>
__global__ __launch_bounds__(256) void gemm_bt(const unsigned short* __restrict__ A,
                                               const unsigned short* __restrict__ Bw,
                                               const float* __restrict__ bias,
                                               void* __restrict__ Out, float oscale) {
    __shared__ unsigned short sA[128*32];
    __shared__ unsigned short sB[128*32];
    const int tid = threadIdx.x;
    const int w  = tid >> 6, l = tid & 63;
    const int lg = l >> 4,  lr = l & 15;
    const int mBase = blockIdx.y * 128;
    const int nBase = blockIdx.x * 128;
    const int wr = w >> 1, wc = w & 1;
    const int srow = l >> 2;
    const int sk0  = (l & 3) * 8;

    f32x4 acc[4][4] = {};

    for (int kb = 0; kb < EMB; kb += 32) {
        __syncthreads();
        #pragma unroll
        for (int rr = 0; rr < 2; ++rr) {
            const int chunk = w + rr * 4;
            const unsigned short* ga = A  + (size_t)(mBase + chunk*16 + srow) * EMB + kb + sk0;
            GLDS(ga, &sA[chunk * 512]);
            const unsigned short* gb = Bw + (size_t)(nBase + chunk*16 + srow) * EMB + kb + sk0;
            GLDS(gb, &sB[chunk * 512]);
        }
        __syncthreads();
        s16x8 af[4], bf[4];
        #pragma unroll
        for (int mi = 0; mi < 4; ++mi)
            af[mi] = *reinterpret_cast<const s16x8*>(&sA[(wr*64 + mi*16 + lr)*32 + lg*8]);
        #pragma unroll
        for (int ni = 0; ni < 4; ++ni)
            bf[ni] = *reinterpret_cast<const s16x8*>(&sB[(wc*64 + ni*16 + lr)*32 + lg*8]);
        #pragma unroll
        for (int mi = 0; mi < 4; ++mi)
            #pragma unroll
            for (int ni = 0; ni < 4; ++ni) {
                if (EPI == 2)
                    acc[ni][mi] = mfma16(bf[ni], af[mi], acc[ni][mi]);  // C^T: rows=n, cols=token
                else
                    acc[mi][ni] = mfma16(af[mi], bf[ni], acc[mi][ni]);
            }
    }

    const int colBase = nBase + wc * 64;
    const int rowBase = mBase + wr * 64;
    if (EPI == 0) {
        unsigned short* outp = (unsigned short*)Out;
        #pragma unroll
        for (int ni = 0; ni < 4; ++ni) {
            const int col = colBase + ni*16 + lr;
            const float bv = bias[col];
            const int h = col >> 6, d = col & 63;
            #pragma unroll
            for (int mi = 0; mi < 4; ++mi) {
                #pragma unroll
                for (int r = 0; r < 4; ++r) {
                    const int gr = rowBase + mi*16 + lg*4 + r;
                    const int b = gr >> 11, s = gr & 2047;
                    outp[((size_t)(b*NH + h) * SEQ + s) * DHEAD + d] = f2bf((acc[mi][ni][r] + bv) * oscale);
                }
            }
        }
    } else if (EPI == 1) {
        float* outp = (float*)Out;
        #pragma unroll
        for (int ni = 0; ni < 4; ++ni) {
            const int col = colBase + ni*16 + lr;
            const float bv = bias[col];
            #pragma unroll
            for (int mi = 0; mi < 4; ++mi) {
                #pragma unroll
                for (int r = 0; r < 4; ++r) {
                    const int gr = rowBase + mi*16 + lg*4 + r;
                    outp[(size_t)gr * EMB + col] = acc[mi][ni][r] + bv;
                }
            }
        }
    } else {
        // EPI==2: acc[ni][mi] holds C^T: row = n (weight out-dim), col = token
        unsigned short* outp = (unsigned short*)Out;
        #pragma unroll
        for (int ni = 0; ni < 4; ++ni) {
            #pragma unroll
            for (int r = 0; r < 4; ++r) {
                const int n = nBase + wc*64 + ni*16 + lg*4 + r;
                const float bv = bias[n];
                const int h = n >> 6, d = n & 63;
                #pragma unroll
                for (int mi = 0; mi < 4; ++mi) {
                    const int tok = rowBase + mi*16 + lr;
                    const int b = tok >> 11, s = tok & 2047;
                    outp[((size_t)(b*NH + h) * DHEAD + d) * SEQ + s] = f2bf(acc[ni][mi][r] + bv);
                }
            }
        }
    }
}

// ---------------- flash attention (causal), swapped-operand 32x32 MFMA ----------------
// grid: (SEQ/128, B*H), block 256 = 4 waves. Each wave owns a 32-row q-strip,
// fully independent: NO barriers, NO main-loop LDS. K/V^T fragments read
// directly from global (L2-resident: 256KB per head each).
// S^T = mfma(A=K, B=Q)  -> lane owns q=lane&31, kv=(reg&3)+8*(reg>>2)+4*hi
// o^T = mfma(A=V^T, B=P^T) -> lane owns q=lane&31, d=(reg&3)+8*(reg>>2)+4*hi (+32*dt)
__global__ __launch_bounds__(256) void attn_fwd(const unsigned short* __restrict__ qb,
                                                const unsigned short* __restrict__ kb,
                                                const unsigned short* __restrict__ vtb,
                                                unsigned short* __restrict__ ctx) {
    __shared__ __align__(16) unsigned sld[4][32*36];
    const int tid = threadIdx.x;
    const int w = tid >> 6, l = tid & 63;
    const int l31 = l & 31, hi = l >> 5;
    const int bh = blockIdx.y;
    const int q0 = ((int)gridDim.x - 1 - (int)blockIdx.x) * 128 + w * 32;  // heavy-first
    const unsigned short* qh = qb  + (size_t)bh * SEQ * DHEAD;
    const unsigned short* kh = kb  + (size_t)bh * SEQ * DHEAD;
    const unsigned short* vh = vtb + (size_t)bh * DHEAD * SEQ;

    // Q fragments (B-operand): col=q=l31, k = s*16 + hi*8 + j.  Q pre-scaled by 0.125 in GEMM.
    s16x8 qf[4];
    #pragma unroll
    for (int s = 0; s < 4; ++s)
        qf[s] = *reinterpret_cast<const s16x8*>(&qh[(size_t)(q0 + l31) * DHEAD + s*16 + hi*8]);

    f32x16 o0 = {}, o1 = {};
    float m = -__builtin_inff(), lsum = 0.f;

    const int ntiles = q0/32 + 1;
    for (int t = 0; t < ntiles; ++t) {
        const int kv0 = t * 32;
        // K fragments (A-operand): row=kv=l31, k = s*16 + hi*8 + j
        s16x8 kf[4];
        #pragma unroll
        for (int s = 0; s < 4; ++s)
            kf[s] = *reinterpret_cast<const s16x8*>(&kh[(size_t)(kv0 + l31) * DHEAD + s*16 + hi*8]);
        // V^T fragments (A-operand for PV): row=d=l31(+32), k = kv = ks*16 + hi*8 + j
        s16x8 vf0[2], vf1[2];
        #pragma unroll
        for (int ks = 0; ks < 2; ++ks) {
            vf0[ks] = *reinterpret_cast<const s16x8*>(&vh[(size_t)l31        * SEQ + kv0 + ks*16 + hi*8]);
            vf1[ks] = *reinterpret_cast<const s16x8*>(&vh[(size_t)(32 + l31) * SEQ + kv0 + ks*16 + hi*8]);
        }

        f32x16 sa = {};
        #pragma unroll
        for (int s = 0; s < 4; ++s) sa = mfma32(kf[s], qf[s], sa);

        if (t == ntiles - 1) {  // diagonal tile: mask kv > q  (kv0 == q0 here)
            #pragma unroll
            for (int r = 0; r < 16; ++r) {
                const int kvloc = (r & 3) + 8*(r >> 2) + 4*hi;
                if (kvloc > l31) sa[r] = -__builtin_inff();
            }
        }

        // online softmax, per-lane (lane owns one q-row) + 1 partner shfl
        float pm = sa[0];
        #pragma unroll
        for (int r = 1; r < 16; ++r) pm = fmaxf(pm, sa[r]);
        pm = fmaxf(pm, __shfl_xor(pm, 32));
        const float mn = fmaxf(m, pm);
        const float fs = __expf(m - mn);
        m = mn;
        float rs = 0.f;
        #pragma unroll
        for (int r = 0; r < 16; ++r) {
            const float p = __expf(sa[r] - mn);
            sa[r] = p; rs += p;
        }
        rs += __shfl_xor(rs, 32);
        lsum = lsum * fs + rs;
        o0 *= fs; o1 *= fs;

        // pack P^T into B-fragments: 8 cvt_pk + 4 permlane32_swap
        unsigned u[4], v[4];
        #pragma unroll
        for (int r2 = 0; r2 < 4; ++r2) {
            u[r2] = cvtpk(sa[4*r2 + 0], sa[4*r2 + 1]);
            v[r2] = cvtpk(sa[4*r2 + 2], sa[4*r2 + 3]);
        }
        plane_swap(u[0], u[1]); plane_swap(v[0], v[1]);
        plane_swap(u[2], u[3]); plane_swap(v[2], v[3]);
        const s16x8 pf0 = frag4(u[0], v[0], u[1], v[1]);  // kv 0..15 of tile
        const s16x8 pf1 = frag4(u[2], v[2], u[3], v[3]);  // kv 16..31

        o0 = mfma32(vf0[0], pf0, o0);
        o0 = mfma32(vf0[1], pf1, o0);
        o1 = mfma32(vf1[0], pf0, o1);
        o1 = mfma32(vf1[1], pf1, o1);
    }

    // ---- epilogue: normalize, wave-local LDS transpose, coalesced store ----
    const float inv = 1.0f / lsum;
    unsigned* my = sld[w];
    #pragma unroll
    for (int dt = 0; dt < 2; ++dt) {
        #pragma unroll
        for (int r2 = 0; r2 < 4; ++r2) {
            const float a0 = (dt ? o1[4*r2+0] : o0[4*r2+0]) * inv;
            const float a1 = (dt ? o1[4*r2+1] : o0[4*r2+1]) * inv;
            const float a2 = (dt ? o1[4*r2+2] : o0[4*r2+2]) * inv;
            const float a3 = (dt ? o1[4*r2+3] : o0[4*r2+3]) * inv;
            const int col = 4*r2 + 2*hi + 16*dt;   // dword col; d = 2*col..2*col+3
            my[l31*36 + col]     = cvtpk(a0, a1);
            my[l31*36 + col + 1] = cvtpk(a2, a3);
        }
    }
    asm volatile("s_waitcnt lgkmcnt(0)" ::: "memory");
    __builtin_amdgcn_sched_barrier(0);
    const int row = l >> 1, half = l & 1;
    const unsigned* rp = &my[row*36 + half*16];
    const int b = bh >> 4, h = bh & 15;
    unsigned short* op = &ctx[((size_t)b*SEQ + q0 + row) * EMB + h*DHEAD + half*32];
    #pragma unroll
    for (int i = 0; i < 4; ++i) {
        uint4 d4 = *reinterpret_cast<const uint4*>(rp + i*4);
        *reinterpret_cast<uint4*>(op + i*8) = d4;
    }
}

// ---------------- launch ----------------
extern "C" void kernel_launch(void* const* d_in, const int* in_sizes, int n_in,
                              void* d_out, int out_size, void* d_ws, size_t ws_size,
                              hipStream_t stream) {
    const float* x  = (const float*)d_in[0];
    const float* wq = (const float*)d_in[1];
    const float* bq = (const float*)d_in[2];
    const float* wk = (const float*)d_in[3];
    const float* bk = (const float*)d_in[4];
    const float* wv = (const float*)d_in[5];
    const float* bv = (const float*)d_in[6];
    const float* wo = (const float*)d_in[7];
    const float* bo = (const float*)d_in[8];
    float* out = (float*)d_out;

    char* ws = (char*)d_ws;
    const size_t MB = 1ull << 20;
    unsigned short* xb  = (unsigned short*)(ws);            // 16 MB; reused as ctx later
    unsigned short* wqb = (unsigned short*)(ws + 16*MB);
    unsigned short* wkb = (unsigned short*)(ws + 18*MB);
    unsigned short* wvb = (unsigned short*)(ws + 20*MB);
    unsigned short* wob = (unsigned short*)(ws + 22*MB);
    unsigned short* qB  = (unsigned short*)(ws + 24*MB);    // [B,H,S,Dh], pre-scaled by 0.125
    unsigned short* kB  = (unsigned short*)(ws + 40*MB);    // [B,H,S,Dh]
    unsigned short* vtB = (unsigned short*)(ws + 56*MB);    // [B,H,Dh,S]
    unsigned short* ctx = xb;

    const int nx4 = MROWS * EMB / 4;
    const int nw4 = EMB * EMB / 4;
    cvt_bf16<<<(nx4 + 255)/256, 256, 0, stream>>>(x,  xb,  nx4);
    cvt_bf16<<<(nw4 + 255)/256, 256, 0, stream>>>(wq, wqb, nw4);
    cvt_bf16<<<(nw4 + 255)/256, 256, 0, stream>>>(wk, wkb, nw4);
    cvt_bf16<<<(nw4 + 255)/256, 256, 0, stream>>>(wv, wvb, nw4);
    cvt_bf16<<<(nw4 + 255)/256, 256, 0, stream>>>(wo, wob, nw4);

    dim3 gg(EMB/128, MROWS/128);  // (8, 64)
    gemm_bt<0><<<gg, 256, 0, stream>>>(xb, wqb, bq, (void*)qB, 0.125f);
    gemm_bt<0><<<gg, 256, 0, stream>>>(xb, wkb, bk, (void*)kB, 1.0f);
    gemm_bt<2><<<gg, 256, 0, stream>>>(xb, wvb, bv, (void*)vtB, 1.0f);

    dim3 ga(SEQ/128, BATCH*NH);   // (16, 64)
    attn_fwd<<<ga, 256, 0, stream>>>(qB, kB, vtB, ctx);

    gemm_bt<1><<<gg, 256, 0, stream>>>(ctx, wob, bo, (void*)out, 1.0f);
}

// Round 3
// 202.081 us; speedup vs baseline: 2.0367x; 2.0367x over previous
//
#include <hip/hip_runtime.h>
#include <hip/hip_bf16.h>

#define EMB   1024
#define SEQ   2048
#define BATCH 4
#define NH    16
#define DHEAD 64
#define MROWS (BATCH*SEQ)   // 8192
#define NSTRIP (SEQ/32)     // 64

typedef float f32x4  __attribute__((ext_vector_type(4)));
typedef float f32x16 __attribute__((ext_vector_type(16)));
typedef short s16x8  __attribute__((ext_vector_type(8)));

__device__ __forceinline__ f32x4 mfma16(s16x8 a, s16x8 b, f32x4 c) {
    return __builtin_amdgcn_mfma_f32_16x16x32_bf16(a, b, c, 0, 0, 0);
}
__device__ __forceinline__ f32x16 mfma32(s16x8 a, s16x8 b, f32x16 c) {
    return __builtin_amdgcn_mfma_f32_32x32x16_bf16(a, b, c, 0, 0, 0);
}

__device__ __forceinline__ unsigned short f2bf(float f) {
    __hip_bfloat16 h = __float2bfloat16(f);
    return __builtin_bit_cast(unsigned short, h);
}

__device__ __forceinline__ unsigned cvtpk(float lo, float hi) {
    unsigned r;
    asm("v_cvt_pk_bf16_f32 %0, %1, %2" : "=v"(r) : "v"(lo), "v"(hi));
    return r;
}

__device__ __forceinline__ void plane_swap(unsigned &a, unsigned &b) {
    asm("v_permlane32_swap_b32 %0, %1" : "+v"(a), "+v"(b));
}

__device__ __forceinline__ s16x8 frag4(unsigned a, unsigned b, unsigned c, unsigned d) {
    union { unsigned u[4]; s16x8 f; } x;
    x.u[0] = a; x.u[1] = b; x.u[2] = c; x.u[3] = d;
    return x.f;
}

// ---------------- fp32 -> bf16 conversion (vectorized) ----------------
__global__ void cvt_bf16(const float* __restrict__ in, unsigned short* __restrict__ out, int n4) {
    int i = blockIdx.x * blockDim.x + threadIdx.x;
    if (i >= n4) return;
    float4 v = reinterpret_cast<const float4*>(in)[i];
    ushort4 o;
    o.x = f2bf(v.x); o.y = f2bf(v.y); o.z = f2bf(v.z); o.w = f2bf(v.w);
    reinterpret_cast<ushort4*>(out)[i] = o;
}

// ---------------- bf16 GEMM: C[M,N] = A[M,K] * B[N,K]^T + bias ----------------
// EPI==0: bf16 fragment-ready Q/K layout [bh][strip32][s=4][hi=2][l31=32][j=8], scaled.
// EPI==1: fp32 row-major + bias.
// EPI==2: bf16 fragment-ready V^T layout [bh][kvt32][ks*2+hi][d=64][j=8].
#define GLDS(g, s) __builtin_amdgcn_global_load_lds((const __attribute__((address_space(1))) void*)(g), \
                       (__attribute__((address_space(3))) void*)(s), 16, 0, 0)

template<int EPI>
__global__ __launch_bounds__(256) void gemm_bt(const unsigned short* __restrict__ A,
                                               const unsigned short* __restrict__ Bw,
                                               const float* __restrict__ bias,
                                               void* __restrict__ Out, float oscale) {
    __shared__ unsigned short sA[128*32];
    __shared__ unsigned short sB[128*32];
    const int tid = threadIdx.x;
    const int w  = tid >> 6, l = tid & 63;
    const int lg = l >> 4,  lr = l & 15;
    const int mBase = blockIdx.y * 128;
    const int nBase = blockIdx.x * 128;
    const int wr = w >> 1, wc = w & 1;
    const int srow = l >> 2;
    const int sk0  = (l & 3) * 8;

    f32x4 acc[4][4] = {};

    for (int kb = 0; kb < EMB; kb += 32) {
        __syncthreads();
        #pragma unroll
        for (int rr = 0; rr < 2; ++rr) {
            const int chunk = w + rr * 4;
            const unsigned short* ga = A  + (size_t)(mBase + chunk*16 + srow) * EMB + kb + sk0;
            GLDS(ga, &sA[chunk * 512]);
            const unsigned short* gb = Bw + (size_t)(nBase + chunk*16 + srow) * EMB + kb + sk0;
            GLDS(gb, &sB[chunk * 512]);
        }
        __syncthreads();
        s16x8 af[4], bf[4];
        #pragma unroll
        for (int mi = 0; mi < 4; ++mi)
            af[mi] = *reinterpret_cast<const s16x8*>(&sA[(wr*64 + mi*16 + lr)*32 + lg*8]);
        #pragma unroll
        for (int ni = 0; ni < 4; ++ni)
            bf[ni] = *reinterpret_cast<const s16x8*>(&sB[(wc*64 + ni*16 + lr)*32 + lg*8]);
        #pragma unroll
        for (int mi = 0; mi < 4; ++mi)
            #pragma unroll
            for (int ni = 0; ni < 4; ++ni) {
                if (EPI == 2)
                    acc[ni][mi] = mfma16(bf[ni], af[mi], acc[ni][mi]);  // C^T: rows=n, cols=token
                else
                    acc[mi][ni] = mfma16(af[mi], bf[ni], acc[mi][ni]);
            }
    }

    const int colBase = nBase + wc * 64;
    const int rowBase = mBase + wr * 64;
    if (EPI == 0) {
        unsigned short* outp = (unsigned short*)Out;
        #pragma unroll
        for (int ni = 0; ni < 4; ++ni) {
            const int col = colBase + ni*16 + lr;
            const float bv = bias[col];
            const int h = col >> 6, d = col & 63;
            const int inner = ((d >> 4) * 2 + ((d >> 3) & 1)) * 256 + (d & 7);
            #pragma unroll
            for (int mi = 0; mi < 4; ++mi) {
                #pragma unroll
                for (int r = 0; r < 4; ++r) {
                    const int gr = rowBase + mi*16 + lg*4 + r;
                    const int b = gr >> 11, sin_ = gr & 2047;
                    const int strip = sin_ >> 5, l31q = sin_ & 31;
                    outp[(size_t)(b*NH + h) * (SEQ*DHEAD) + strip*2048 + inner + l31q*8]
                        = f2bf((acc[mi][ni][r] + bv) * oscale);
                }
            }
        }
    } else if (EPI == 1) {
        float* outp = (float*)Out;
        #pragma unroll
        for (int ni = 0; ni < 4; ++ni) {
            const int col = colBase + ni*16 + lr;
            const float bv = bias[col];
            #pragma unroll
            for (int mi = 0; mi < 4; ++mi) {
                #pragma unroll
                for (int r = 0; r < 4; ++r) {
                    const int gr = rowBase + mi*16 + lg*4 + r;
                    outp[(size_t)gr * EMB + col] = acc[mi][ni][r] + bv;
                }
            }
        }
    } else {
        // EPI==2: acc[ni][mi] holds V^T: row n = out-dim, col = token
        unsigned short* outp = (unsigned short*)Out;
        #pragma unroll
        for (int ni = 0; ni < 4; ++ni) {
            #pragma unroll
            for (int r = 0; r < 4; ++r) {
                const int n = colBase + ni*16 + lg*4 + r;
                const float bv = bias[n];
                const int h = n >> 6, d = n & 63;
                #pragma unroll
                for (int mi = 0; mi < 4; ++mi) {
                    const int tok = rowBase + mi*16 + lr;
                    const int b = tok >> 11, sv = tok & 2047;
                    const int kvt = sv >> 5, ks = (sv >> 4) & 1, hi2 = (sv >> 3) & 1, j = sv & 7;
                    outp[(size_t)(b*NH + h) * (SEQ*DHEAD) + kvt*2048 + (ks*2 + hi2)*512 + d*8 + j]
                        = f2bf(acc[ni][mi][r] + bv);
                }
            }
        }
    }
}

// ---------------- flash attention (causal), swapped-operand 32x32 MFMA ----------------
// 1 wave per block; 4096 blocks. Wave owns 32 q-rows (strip). All K/V/Q loads are
// fragment-ready coalesced (lane l reads base + l*16B). Register-double-buffered
// K/V prefetch; no barriers; softmax fully in-register (1 shfl pair per reduce).
__global__ __launch_bounds__(64) void attn_fwd(const unsigned short* __restrict__ qb,
                                               const unsigned short* __restrict__ kb,
                                               const unsigned short* __restrict__ vb,
                                               unsigned short* __restrict__ ctx) {
    __shared__ __align__(16) unsigned sld[32*36];
    const int l = threadIdx.x;
    const int l31 = l & 31, hi = l >> 5;
    const int bh = blockIdx.x & 63;
    const int strip = (NSTRIP - 1) - ((int)blockIdx.x >> 6);   // mixes depth across CUs
    const int q0 = strip * 32;
    const size_t hbase = (size_t)bh * SEQ * DHEAD;
    const unsigned short* qh = qb + hbase;
    const unsigned short* kh = kb + hbase;
    const unsigned short* vh = vb + hbase;

    s16x8 qf[4];
    #pragma unroll
    for (int s = 0; s < 4; ++s)
        qf[s] = *reinterpret_cast<const s16x8*>(&qh[strip*2048 + s*512 + l*8]);

    f32x16 o0 = {}, o1 = {};
    float m = -__builtin_inff(), lsum = 0.f;
    const int ntiles = strip + 1;

    s16x8 kfA[4], vfA[4], kfB[4], vfB[4];

    auto LOADKV = [&](s16x8* kf, s16x8* vf, int t) {
        const unsigned short* kp = kh + t*2048;
        #pragma unroll
        for (int s = 0; s < 4; ++s)
            kf[s] = *reinterpret_cast<const s16x8*>(&kp[s*512 + l*8]);
        const unsigned short* vp = vh + t*2048 + hi*512 + l31*8;
        #pragma unroll
        for (int ks = 0; ks < 2; ++ks) {
            vf[ks]     = *reinterpret_cast<const s16x8*>(&vp[ks*1024]);
            vf[2 + ks] = *reinterpret_cast<const s16x8*>(&vp[ks*1024 + 256]);
        }
    };

    auto BODY = [&](s16x8* kf, s16x8* vf, int t) {
        f32x16 sa = {};
        #pragma unroll
        for (int s = 0; s < 4; ++s) sa = mfma32(kf[s], qf[s], sa);

        if (t == strip) {  // diagonal tile: mask kv > q
            #pragma unroll
            for (int r = 0; r < 16; ++r) {
                const int kvloc = (r & 3) + 8*(r >> 2) + 4*hi;
                if (kvloc > l31) sa[r] = -__builtin_inff();
            }
        }

        float mx[16];
        #pragma unroll
        for (int r = 0; r < 16; ++r) mx[r] = sa[r];
        #pragma unroll
        for (int st = 8; st >= 1; st >>= 1)
            #pragma unroll
            for (int i = 0; i < st; ++i) mx[i] = fmaxf(mx[i], mx[i + st]);
        float pm = fmaxf(mx[0], __shfl_xor(mx[0], 32));

        float mn = m;
        if (!__all(pm <= m + 5.5f)) {       // T13 defer-max (nat-log domain)
            mn = fmaxf(m, pm);
            const float fs = __expf(m - mn);
            o0 *= fs; o1 *= fs; lsum *= fs;
            m = mn;
        }

        float p[16];
        #pragma unroll
        for (int r = 0; r < 16; ++r) p[r] = __expf(sa[r] - mn);
        float sm[16];
        #pragma unroll
        for (int r = 0; r < 16; ++r) sm[r] = p[r];
        #pragma unroll
        for (int st = 8; st >= 1; st >>= 1)
            #pragma unroll
            for (int i = 0; i < st; ++i) sm[i] += sm[i + st];
        lsum += sm[0] + __shfl_xor(sm[0], 32);

        unsigned u[4], v[4];
        #pragma unroll
        for (int r2 = 0; r2 < 4; ++r2) {
            u[r2] = cvtpk(p[4*r2 + 0], p[4*r2 + 1]);
            v[r2] = cvtpk(p[4*r2 + 2], p[4*r2 + 3]);
        }
        plane_swap(u[0], u[1]); plane_swap(v[0], v[1]);
        plane_swap(u[2], u[3]); plane_swap(v[2], v[3]);
        const s16x8 pf0 = frag4(u[0], v[0], u[1], v[1]);
        const s16x8 pf1 = frag4(u[2], v[2], u[3], v[3]);

        o0 = mfma32(vf[0], pf0, o0);
        o0 = mfma32(vf[1], pf1, o0);
        o1 = mfma32(vf[2], pf0, o1);
        o1 = mfma32(vf[3], pf1, o1);
    };

    LOADKV(kfA, vfA, 0);
    int t = 0;
    for (; t + 1 < ntiles; t += 2) {
        LOADKV(kfB, vfB, t + 1);
        BODY(kfA, vfA, t);
        if (t + 2 < ntiles) LOADKV(kfA, vfA, t + 2);
        BODY(kfB, vfB, t + 1);
    }
    if (t < ntiles) BODY(kfA, vfA, t);

    // ---- epilogue: normalize, wave-local LDS transpose, coalesced store ----
    const float inv = 1.0f / lsum;
    #pragma unroll
    for (int dt = 0; dt < 2; ++dt) {
        #pragma unroll
        for (int r2 = 0; r2 < 4; ++r2) {
            const float a0 = (dt ? o1[4*r2+0] : o0[4*r2+0]) * inv;
            const float a1 = (dt ? o1[4*r2+1] : o0[4*r2+1]) * inv;
            const float a2 = (dt ? o1[4*r2+2] : o0[4*r2+2]) * inv;
            const float a3 = (dt ? o1[4*r2+3] : o0[4*r2+3]) * inv;
            const int col = 4*r2 + 2*hi + 16*dt;
            sld[l31*36 + col]     = cvtpk(a0, a1);
            sld[l31*36 + col + 1] = cvtpk(a2, a3);
        }
    }
    asm volatile("s_waitcnt lgkmcnt(0)" ::: "memory");
    __builtin_amdgcn_sched_barrier(0);
    const int row = l >> 1, half = l & 1;
    const unsigned* rp = &sld[row*36 + half*16];
    const int b = bh >> 4, h = bh & 15;
    unsigned short* op = &ctx[((size_t)b*SEQ + q0 + row) * EMB + h*DHEAD + half*32];
    #pragma unroll
    for (int i = 0; i < 4; ++i) {
        uint4 d4 = *reinterpret_cast<const uint4*>(rp + i*4);
        *reinterpret_cast<uint4*>(op + i*8) = d4;
    }
}

// ---------------- launch ----------------
extern "C" void kernel_launch(void* const* d_in, const int* in_sizes, int n_in,
                              void* d_out, int out_size, void* d_ws, size_t ws_size,
                              hipStream_t stream) {
    const float* x  = (const float*)d_in[0];
    const float* wq = (const float*)d_in[1];
    const float* bq = (const float*)d_in[2];
    const float* wk = (const float*)d_in[3];
    const float* bk = (const float*)d_in[4];
    const float* wv = (const float*)d_in[5];
    const float* bv = (const float*)d_in[6];
    const float* wo = (const float*)d_in[7];
    const float* bo = (const float*)d_in[8];
    float* out = (float*)d_out;

    char* ws = (char*)d_ws;
    const size_t MB = 1ull << 20;
    unsigned short* xb  = (unsigned short*)(ws);            // 16 MB; reused as ctx later
    unsigned short* wqb = (unsigned short*)(ws + 16*MB);
    unsigned short* wkb = (unsigned short*)(ws + 18*MB);
    unsigned short* wvb = (unsigned short*)(ws + 20*MB);
    unsigned short* wob = (unsigned short*)(ws + 22*MB);
    unsigned short* qB  = (unsigned short*)(ws + 24*MB);    // fragment-ready, pre-scaled
    unsigned short* kB  = (unsigned short*)(ws + 40*MB);    // fragment-ready
    unsigned short* vtB = (unsigned short*)(ws + 56*MB);    // fragment-ready V^T
    unsigned short* ctx = xb;

    const int nx4 = MROWS * EMB / 4;
    const int nw4 = EMB * EMB / 4;
    cvt_bf16<<<(nx4 + 255)/256, 256, 0, stream>>>(x,  xb,  nx4);
    cvt_bf16<<<(nw4 + 255)/256, 256, 0, stream>>>(wq, wqb, nw4);
    cvt_bf16<<<(nw4 + 255)/256, 256, 0, stream>>>(wk, wkb, nw4);
    cvt_bf16<<<(nw4 + 255)/256, 256, 0, stream>>>(wv, wvb, nw4);
    cvt_bf16<<<(nw4 + 255)/256, 256, 0, stream>>>(wo, wob, nw4);

    dim3 gg(EMB/128, MROWS/128);  // (8, 64)
    gemm_bt<0><<<gg, 256, 0, stream>>>(xb, wqb, bq, (void*)qB, 0.125f);
    gemm_bt<0><<<gg, 256, 0, stream>>>(xb, wkb, bk, (void*)kB, 1.0f);
    gemm_bt<2><<<gg, 256, 0, stream>>>(xb, wvb, bv, (void*)vtB, 1.0f);

    attn_fwd<<<dim3(NSTRIP * BATCH * NH), 64, 0, stream>>>(qB, kB, vtB, ctx);

    gemm_bt<1><<<gg, 256, 0, stream>>>(ctx, wob, bo, (void*)out, 1.0f);
}

// Round 5
// 184.880 us; speedup vs baseline: 2.2262x; 1.0930x over previous
//
#include <hip/hip_runtime.h>
#include <hip/hip_bf16.h>

#define EMB   1024
#define SEQ   2048
#define BATCH 4
#define NH    16
#define DHEAD 64
#define MROWS (BATCH*SEQ)   // 8192
#define NSTRIP (SEQ/32)     // 64
#define QSCALE 0.18033688011112042f  // 0.125 * log2(e): softmax in exp2 domain

typedef float f32x4  __attribute__((ext_vector_type(4)));
typedef float f32x16 __attribute__((ext_vector_type(16)));
typedef short s16x8  __attribute__((ext_vector_type(8)));

__device__ __forceinline__ f32x4 mfma16(s16x8 a, s16x8 b, f32x4 c) {
    return __builtin_amdgcn_mfma_f32_16x16x32_bf16(a, b, c, 0, 0, 0);
}
__device__ __forceinline__ f32x16 mfma32(s16x8 a, s16x8 b, f32x16 c) {
    return __builtin_amdgcn_mfma_f32_32x32x16_bf16(a, b, c, 0, 0, 0);
}

__device__ __forceinline__ unsigned short f2bf(float f) {
    __hip_bfloat16 h = __float2bfloat16(f);
    return __builtin_bit_cast(unsigned short, h);
}

__device__ __forceinline__ unsigned cvtpk(float lo, float hi) {
    unsigned r;
    asm("v_cvt_pk_bf16_f32 %0, %1, %2" : "=v"(r) : "v"(lo), "v"(hi));
    return r;
}

__device__ __forceinline__ void plane_swap(unsigned &a, unsigned &b) {
    asm("v_permlane32_swap_b32 %0, %1" : "+v"(a), "+v"(b));
}

__device__ __forceinline__ s16x8 frag4(unsigned a, unsigned b, unsigned c, unsigned d) {
    union { unsigned u[4]; s16x8 f; } x;
    x.u[0] = a; x.u[1] = b; x.u[2] = c; x.u[3] = d;
    return x.f;
}

__device__ __forceinline__ float exp2r(float x) {   // raw v_exp_f32 (2^x)
    float r;
    asm("v_exp_f32 %0, %1" : "=v"(r) : "v"(x));
    return r;
}
__device__ __forceinline__ float max3f(float a, float b, float c) {
    float r;
    asm("v_max3_f32 %0, %1, %2, %3" : "=v"(r) : "v"(a), "v"(b), "v"(c));
    return r;
}

// ---------------- fp32 -> bf16 conversion ----------------
__global__ void cvt_bf16(const float* __restrict__ in, unsigned short* __restrict__ out, int n4) {
    int i = blockIdx.x * blockDim.x + threadIdx.x;
    if (i >= n4) return;
    float4 v = reinterpret_cast<const float4*>(in)[i];
    ushort4 o;
    o.x = f2bf(v.x); o.y = f2bf(v.y); o.z = f2bf(v.z); o.w = f2bf(v.w);
    reinterpret_cast<ushort4*>(out)[i] = o;
}

// all 4 weight matrices in one launch (grid.y selects tensor)
__global__ void cvt_bf16_w(const float* __restrict__ w0, const float* __restrict__ w1,
                           const float* __restrict__ w2, const float* __restrict__ w3,
                           unsigned short* __restrict__ o0, unsigned short* __restrict__ o1,
                           unsigned short* __restrict__ o2, unsigned short* __restrict__ o3,
                           int n4) {
    int i = blockIdx.x * blockDim.x + threadIdx.x;
    if (i >= n4) return;
    const float* in; unsigned short* out;
    switch (blockIdx.y) {
        case 0:  in = w0; out = o0; break;
        case 1:  in = w1; out = o1; break;
        case 2:  in = w2; out = o2; break;
        default: in = w3; out = o3; break;
    }
    float4 v = reinterpret_cast<const float4*>(in)[i];
    ushort4 o;
    o.x = f2bf(v.x); o.y = f2bf(v.y); o.z = f2bf(v.z); o.w = f2bf(v.w);
    reinterpret_cast<ushort4*>(out)[i] = o;
}

#define GLDS(g, s) __builtin_amdgcn_global_load_lds((const __attribute__((address_space(1))) void*)(g), \
                       (__attribute__((address_space(3))) void*)(s), 16, 0, 0)

// ---------------- fused QKV GEMM ----------------
// grid (24, 64): blockIdx.x = seg(0..2)*8 + n-tile; seg 0->Q, 1->K, 2->V.
// Q/K epilogue: fragment-ready [bh][strip32][s=4][hi=2][l31=32][j=8] (Q pre-scaled).
// V epilogue: fragment-ready V^T [bh][kvt32][ks*2+hi][d=64][j=8] (swapped mfma -> C^T).
__global__ __launch_bounds__(256) void gemm_qkv(const unsigned short* __restrict__ A,
                                                const unsigned short* __restrict__ wqb,
                                                const unsigned short* __restrict__ wkb,
                                                const unsigned short* __restrict__ wvb,
                                                const float* __restrict__ bq,
                                                const float* __restrict__ bk,
                                                const float* __restrict__ bv,
                                                unsigned short* __restrict__ qB,
                                                unsigned short* __restrict__ kB,
                                                unsigned short* __restrict__ vtB) {
    __shared__ unsigned short sA[128*32];
    __shared__ unsigned short sB[128*32];
    const int tid = threadIdx.x;
    const int w  = tid >> 6, l = tid & 63;
    const int lg = l >> 4,  lr = l & 15;
    const int nb  = blockIdx.x;
    const int seg = nb >> 3;
    const int mBase = blockIdx.y * 128;
    const int nBase = (nb & 7) * 128;
    const unsigned short* Bw = (seg == 0) ? wqb : (seg == 1) ? wkb : wvb;
    const float* bias = (seg == 0) ? bq : (seg == 1) ? bk : bv;
    const int wr = w >> 1, wc = w & 1;
    const int srow = l >> 2;
    const int sk0  = (l & 3) * 8;
    const bool segV = (seg == 2);

    f32x4 acc[4][4] = {};

    for (int kb = 0; kb < EMB; kb += 32) {
        __syncthreads();
        #pragma unroll
        for (int rr = 0; rr < 2; ++rr) {
            const int chunk = w + rr * 4;
            const unsigned short* ga = A  + (size_t)(mBase + chunk*16 + srow) * EMB + kb + sk0;
            GLDS(ga, &sA[chunk * 512]);
            const unsigned short* gb = Bw + (size_t)(nBase + chunk*16 + srow) * EMB + kb + sk0;
            GLDS(gb, &sB[chunk * 512]);
        }
        __syncthreads();
        s16x8 af[4], bf[4];
        #pragma unroll
        for (int mi = 0; mi < 4; ++mi)
            af[mi] = *reinterpret_cast<const s16x8*>(&sA[(wr*64 + mi*16 + lr)*32 + lg*8]);
        #pragma unroll
        for (int ni = 0; ni < 4; ++ni)
            bf[ni] = *reinterpret_cast<const s16x8*>(&sB[(wc*64 + ni*16 + lr)*32 + lg*8]);
        if (segV) {
            #pragma unroll
            for (int mi = 0; mi < 4; ++mi)
                #pragma unroll
                for (int ni = 0; ni < 4; ++ni)
                    acc[ni][mi] = mfma16(bf[ni], af[mi], acc[ni][mi]);  // C^T
        } else {
            #pragma unroll
            for (int mi = 0; mi < 4; ++mi)
                #pragma unroll
                for (int ni = 0; ni < 4; ++ni)
                    acc[mi][ni] = mfma16(af[mi], bf[ni], acc[mi][ni]);
        }
    }

    const int colBase = nBase + wc * 64;
    const int rowBase = mBase + wr * 64;
    if (!segV) {
        unsigned short* outp = seg ? kB : qB;
        const float oscale = seg ? 1.0f : QSCALE;
        #pragma unroll
        for (int ni = 0; ni < 4; ++ni) {
            const int col = colBase + ni*16 + lr;
            const float bv = bias[col];
            const int h = col >> 6, d = col & 63;
            const int inner = ((d >> 4) * 2 + ((d >> 3) & 1)) * 256 + (d & 7);
            #pragma unroll
            for (int mi = 0; mi < 4; ++mi) {
                #pragma unroll
                for (int r = 0; r < 4; ++r) {
                    const int gr = rowBase + mi*16 + lg*4 + r;
                    const int b = gr >> 11, sin_ = gr & 2047;
                    const int strip = sin_ >> 5, l31q = sin_ & 31;
                    outp[(size_t)(b*NH + h) * (SEQ*DHEAD) + strip*2048 + inner + l31q*8]
                        = f2bf((acc[mi][ni][r] + bv) * oscale);
                }
            }
        }
    } else {
        unsigned short* outp = vtB;
        #pragma unroll
        for (int ni = 0; ni < 4; ++ni) {
            #pragma unroll
            for (int r = 0; r < 4; ++r) {
                const int n = colBase + ni*16 + lg*4 + r;
                const float bv = bias[n];
                const int h = n >> 6, d = n & 63;
                #pragma unroll
                for (int mi = 0; mi < 4; ++mi) {
                    const int tok = rowBase + mi*16 + lr;
                    const int b = tok >> 11, sv = tok & 2047;
                    const int kvt = sv >> 5, ks = (sv >> 4) & 1, hi2 = (sv >> 3) & 1, j = sv & 7;
                    outp[(size_t)(b*NH + h) * (SEQ*DHEAD) + kvt*2048 + (ks*2 + hi2)*512 + d*8 + j]
                        = f2bf(acc[ni][mi][r] + bv);
                }
            }
        }
    }
}

// ---------------- output projection GEMM (fp32 out + bias) ----------------
__global__ __launch_bounds__(256) void gemm_out(const unsigned short* __restrict__ A,
                                                const unsigned short* __restrict__ Bw,
                                                const float* __restrict__ bias,
                                                float* __restrict__ Out) {
    __shared__ unsigned short sA[128*32];
    __shared__ unsigned short sB[128*32];
    const int tid = threadIdx.x;
    const int w  = tid >> 6, l = tid & 63;
    const int lg = l >> 4,  lr = l & 15;
    const int mBase = blockIdx.y * 128;
    const int nBase = blockIdx.x * 128;
    const int wr = w >> 1, wc = w & 1;
    const int srow = l >> 2;
    const int sk0  = (l & 3) * 8;

    f32x4 acc[4][4] = {};

    for (int kb = 0; kb < EMB; kb += 32) {
        __syncthreads();
        #pragma unroll
        for (int rr = 0; rr < 2; ++rr) {
            const int chunk = w + rr * 4;
            const unsigned short* ga = A  + (size_t)(mBase + chunk*16 + srow) * EMB + kb + sk0;
            GLDS(ga, &sA[chunk * 512]);
            const unsigned short* gb = Bw + (size_t)(nBase + chunk*16 + srow) * EMB + kb + sk0;
            GLDS(gb, &sB[chunk * 512]);
        }
        __syncthreads();
        s16x8 af[4], bf[4];
        #pragma unroll
        for (int mi = 0; mi < 4; ++mi)
            af[mi] = *reinterpret_cast<const s16x8*>(&sA[(wr*64 + mi*16 + lr)*32 + lg*8]);
        #pragma unroll
        for (int ni = 0; ni < 4; ++ni)
            bf[ni] = *reinterpret_cast<const s16x8*>(&sB[(wc*64 + ni*16 + lr)*32 + lg*8]);
        #pragma unroll
        for (int mi = 0; mi < 4; ++mi)
            #pragma unroll
            for (int ni = 0; ni < 4; ++ni)
                acc[mi][ni] = mfma16(af[mi], bf[ni], acc[mi][ni]);
    }

    const int colBase = nBase + wc * 64;
    const int rowBase = mBase + wr * 64;
    #pragma unroll
    for (int ni = 0; ni < 4; ++ni) {
        const int col = colBase + ni*16 + lr;
        const float bv = bias[col];
        #pragma unroll
        for (int mi = 0; mi < 4; ++mi) {
            #pragma unroll
            for (int r = 0; r < 4; ++r) {
                const int gr = rowBase + mi*16 + lg*4 + r;
                Out[(size_t)gr * EMB + col] = acc[mi][ni][r] + bv;
            }
        }
    }
}

// ---------------- flash attention (causal), swapped-operand 32x32 MFMA ----------------
// 1 wave per block; 4096 blocks. softmax in exp2 domain (Q pre-scaled by 0.125*log2e).
__global__ __launch_bounds__(64) void attn_fwd(const unsigned short* __restrict__ qb,
                                               const unsigned short* __restrict__ kb,
                                               const unsigned short* __restrict__ vb,
                                               unsigned short* __restrict__ ctx) {
    __shared__ __align__(16) unsigned sld[32*36];
    const int l = threadIdx.x;
    const int l31 = l & 31, hi = l >> 5;
    const int bh = blockIdx.x & 63;
    const int strip = (NSTRIP - 1) - ((int)blockIdx.x >> 6);   // mixes depth across CUs
    const int q0 = strip * 32;
    const size_t hbase = (size_t)bh * SEQ * DHEAD;
    const unsigned short* qh = qb + hbase;
    const unsigned short* kh = kb + hbase;
    const unsigned short* vh = vb + hbase;

    s16x8 qf[4];
    #pragma unroll
    for (int s = 0; s < 4; ++s)
        qf[s] = *reinterpret_cast<const s16x8*>(&qh[strip*2048 + s*512 + l*8]);

    f32x16 o0 = {}, o1 = {};
    float m = -__builtin_inff(), lsum = 0.f;
    const int ntiles = strip + 1;

    s16x8 kfA[4], vfA[4], kfB[4], vfB[4];

    auto LOADKV = [&](s16x8* kf, s16x8* vf, int t) {
        const unsigned short* kp = kh + t*2048;
        #pragma unroll
        for (int s = 0; s < 4; ++s)
            kf[s] = *reinterpret_cast<const s16x8*>(&kp[s*512 + l*8]);
        const unsigned short* vp = vh + t*2048 + hi*512 + l31*8;
        #pragma unroll
        for (int ks = 0; ks < 2; ++ks) {
            vf[ks]     = *reinterpret_cast<const s16x8*>(&vp[ks*1024]);
            vf[2 + ks] = *reinterpret_cast<const s16x8*>(&vp[ks*1024 + 256]);
        }
    };

    auto BODY = [&](s16x8* kf, s16x8* vf, int t) {
        f32x16 sa = {};
        #pragma unroll
        for (int s = 0; s < 4; ++s) sa = mfma32(kf[s], qf[s], sa);

        if (t == strip) {  // diagonal tile: mask kv > q
            #pragma unroll
            for (int r = 0; r < 16; ++r) {
                const int kvloc = (r & 3) + 8*(r >> 2) + 4*hi;
                if (kvloc > l31) sa[r] = -__builtin_inff();
            }
        }

        // max reduce: 5+2 v_max3 + 1 fmax + 1 shfl
        const float a0 = max3f(sa[0],  sa[1],  sa[2]);
        const float a1 = max3f(sa[3],  sa[4],  sa[5]);
        const float a2 = max3f(sa[6],  sa[7],  sa[8]);
        const float a3 = max3f(sa[9],  sa[10], sa[11]);
        const float a4 = max3f(sa[12], sa[13], sa[14]);
        const float b0 = max3f(a0, a1, a2);
        const float b1 = max3f(a3, a4, sa[15]);
        float pm = fmaxf(b0, b1);
        pm = fmaxf(pm, __shfl_xor(pm, 32));

        float mn = m;
        if (!__all(pm <= m + 8.0f)) {        // T13 defer-max (log2 domain: p <= 256)
            mn = fmaxf(m, pm);
            const float fs = exp2r(m - mn);
            o0 *= fs; o1 *= fs; lsum *= fs;
            m = mn;
        }

        #pragma unroll
        for (int r = 0; r < 16; ++r) sa[r] = exp2r(sa[r] - mn);   // in-place

        // sum tree (explicit temps, no array copies)
        const float s0 = sa[0]+sa[1],   s1 = sa[2]+sa[3],   s2 = sa[4]+sa[5],   s3 = sa[6]+sa[7];
        const float s4 = sa[8]+sa[9],   s5 = sa[10]+sa[11], s6 = sa[12]+sa[13], s7 = sa[14]+sa[15];
        const float t0 = s0+s1, t1 = s2+s3, t2 = s4+s5, t3 = s6+s7;
        float rs = (t0+t1) + (t2+t3);
        rs += __shfl_xor(rs, 32);
        lsum += rs;

        unsigned u[4], v[4];
        #pragma unroll
        for (int r2 = 0; r2 < 4; ++r2) {
            u[r2] = cvtpk(sa[4*r2 + 0], sa[4*r2 + 1]);
            v[r2] = cvtpk(sa[4*r2 + 2], sa[4*r2 + 3]);
        }
        plane_swap(u[0], u[1]); plane_swap(v[0], v[1]);
        plane_swap(u[2], u[3]); plane_swap(v[2], v[3]);
        const s16x8 pf0 = frag4(u[0], v[0], u[1], v[1]);
        const s16x8 pf1 = frag4(u[2], v[2], u[3], v[3]);

        o0 = mfma32(vf[0], pf0, o0);
        o0 = mfma32(vf[1], pf1, o0);
        o1 = mfma32(vf[2], pf0, o1);
        o1 = mfma32(vf[3], pf1, o1);
    };

    LOADKV(kfA, vfA, 0);
    int t = 0;
    for (; t + 1 < ntiles; t += 2) {
        LOADKV(kfB, vfB, t + 1);
        BODY(kfA, vfA, t);
        if (t + 2 < ntiles) LOADKV(kfA, vfA, t + 2);
        BODY(kfB, vfB, t + 1);
    }
    if (t < ntiles) BODY(kfA, vfA, t);

    // ---- epilogue: normalize, wave-local LDS transpose, coalesced store ----
    const float inv = 1.0f / lsum;
    #pragma unroll
    for (int dt = 0; dt < 2; ++dt) {
        #pragma unroll
        for (int r2 = 0; r2 < 4; ++r2) {
            const float e0 = (dt ? o1[4*r2+0] : o0[4*r2+0]) * inv;
            const float e1 = (dt ? o1[4*r2+1] : o0[4*r2+1]) * inv;
            const float e2 = (dt ? o1[4*r2+2] : o0[4*r2+2]) * inv;
            const float e3 = (dt ? o1[4*r2+3] : o0[4*r2+3]) * inv;
            const int col = 4*r2 + 2*hi + 16*dt;
            sld[l31*36 + col]     = cvtpk(e0, e1);
            sld[l31*36 + col + 1] = cvtpk(e2, e3);
        }
    }
    asm volatile("s_waitcnt lgkmcnt(0)" ::: "memory");
    __builtin_amdgcn_sched_barrier(0);
    const int row = l >> 1, half = l & 1;
    const unsigned* rp = &sld[row*36 + half*16];
    const int b = bh >> 4, h = bh & 15;
    unsigned short* op = &ctx[((size_t)b*SEQ + q0 + row) * EMB + h*DHEAD + half*32];
    #pragma unroll
    for (int i = 0; i < 4; ++i) {
        uint4 d4 = *reinterpret_cast<const uint4*>(rp + i*4);
        *reinterpret_cast<uint4*>(op + i*8) = d4;
    }
}

// ---------------- launch ----------------
extern "C" void kernel_launch(void* const* d_in, const int* in_sizes, int n_in,
                              void* d_out, int out_size, void* d_ws, size_t ws_size,
                              hipStream_t stream) {
    const float* x  = (const float*)d_in[0];
    const float* wq = (const float*)d_in[1];
    const float* bq = (const float*)d_in[2];
    const float* wk = (const float*)d_in[3];
    const float* bk = (const float*)d_in[4];
    const float* wv = (const float*)d_in[5];
    const float* bv = (const float*)d_in[6];
    const float* wo = (const float*)d_in[7];
    const float* bo = (const float*)d_in[8];
    float* out = (float*)d_out;

    char* ws = (char*)d_ws;
    const size_t MB = 1ull << 20;
    unsigned short* xb  = (unsigned short*)(ws);            // 16 MB; reused as ctx later
    unsigned short* wqb = (unsigned short*)(ws + 16*MB);
    unsigned short* wkb = (unsigned short*)(ws + 18*MB);
    unsigned short* wvb = (unsigned short*)(ws + 20*MB);
    unsigned short* wob = (unsigned short*)(ws + 22*MB);
    unsigned short* qB  = (unsigned short*)(ws + 24*MB);    // fragment-ready, pre-scaled (exp2 domain)
    unsigned short* kB  = (unsigned short*)(ws + 40*MB);    // fragment-ready
    unsigned short* vtB = (unsigned short*)(ws + 56*MB);    // fragment-ready V^T
    unsigned short* ctx = xb;

    const int nx4 = MROWS * EMB / 4;
    const int nw4 = EMB * EMB / 4;
    cvt_bf16<<<(nx4 + 255)/256, 256, 0, stream>>>(x, xb, nx4);
    cvt_bf16_w<<<dim3((nw4 + 255)/256, 4), 256, 0, stream>>>(wq, wk, wv, wo, wqb, wkb, wvb, wob, nw4);

    gemm_qkv<<<dim3(24, MROWS/128), 256, 0, stream>>>(xb, wqb, wkb, wvb, bq, bk, bv, qB, kB, vtB);

    attn_fwd<<<dim3(NSTRIP * BATCH * NH), 64, 0, stream>>>(qB, kB, vtB, ctx);

    gemm_out<<<dim3(EMB/128, MROWS/128), 256, 0, stream>>>(ctx, wob, bo, out);
}

// Round 6
// 183.807 us; speedup vs baseline: 2.2392x; 1.0058x over previous
//
#include <hip/hip_runtime.h>
#include <hip/hip_bf16.h>

#define EMB   1024
#define SEQ   2048
#define BATCH 4
#define NH    16
#define DHEAD 64
#define MROWS (BATCH*SEQ)   // 8192
#define NSTRIP (SEQ/32)     // 64
#define QSCALE 0.18033688011112042f  // 0.125 * log2(e): softmax in exp2 domain

typedef float f32x4  __attribute__((ext_vector_type(4)));
typedef float f32x16 __attribute__((ext_vector_type(16)));
typedef short s16x8  __attribute__((ext_vector_type(8)));

__device__ __forceinline__ f32x4 mfma16(s16x8 a, s16x8 b, f32x4 c) {
    return __builtin_amdgcn_mfma_f32_16x16x32_bf16(a, b, c, 0, 0, 0);
}
__device__ __forceinline__ f32x16 mfma32(s16x8 a, s16x8 b, f32x16 c) {
    return __builtin_amdgcn_mfma_f32_32x32x16_bf16(a, b, c, 0, 0, 0);
}

__device__ __forceinline__ unsigned short f2bf(float f) {
    __hip_bfloat16 h = __float2bfloat16(f);
    return __builtin_bit_cast(unsigned short, h);
}

__device__ __forceinline__ unsigned cvtpk(float lo, float hi) {
    unsigned r;
    asm("v_cvt_pk_bf16_f32 %0, %1, %2" : "=v"(r) : "v"(lo), "v"(hi));
    return r;
}

__device__ __forceinline__ void plane_swap(unsigned &a, unsigned &b) {
    asm("v_permlane32_swap_b32 %0, %1" : "+v"(a), "+v"(b));
}

__device__ __forceinline__ s16x8 frag4(unsigned a, unsigned b, unsigned c, unsigned d) {
    union { unsigned u[4]; s16x8 f; } x;
    x.u[0] = a; x.u[1] = b; x.u[2] = c; x.u[3] = d;
    return x.f;
}

__device__ __forceinline__ float exp2r(float x) {   // raw v_exp_f32 (2^x)
    float r;
    asm("v_exp_f32 %0, %1" : "=v"(r) : "v"(x));
    return r;
}
__device__ __forceinline__ float max3f(float a, float b, float c) {
    float r;
    asm("v_max3_f32 %0, %1, %2, %3" : "=v"(r) : "v"(a), "v"(b), "v"(c));
    return r;
}

// ---------------- fp32 -> bf16 conversion ----------------
__global__ void cvt_bf16(const float* __restrict__ in, unsigned short* __restrict__ out, int n4) {
    int i = blockIdx.x * blockDim.x + threadIdx.x;
    if (i >= n4) return;
    float4 v = reinterpret_cast<const float4*>(in)[i];
    ushort4 o;
    o.x = f2bf(v.x); o.y = f2bf(v.y); o.z = f2bf(v.z); o.w = f2bf(v.w);
    reinterpret_cast<ushort4*>(out)[i] = o;
}

// all 4 weight matrices in one launch (grid.y selects tensor)
__global__ void cvt_bf16_w(const float* __restrict__ w0, const float* __restrict__ w1,
                           const float* __restrict__ w2, const float* __restrict__ w3,
                           unsigned short* __restrict__ o0, unsigned short* __restrict__ o1,
                           unsigned short* __restrict__ o2, unsigned short* __restrict__ o3,
                           int n4) {
    int i = blockIdx.x * blockDim.x + threadIdx.x;
    if (i >= n4) return;
    const float* in; unsigned short* out;
    switch (blockIdx.y) {
        case 0:  in = w0; out = o0; break;
        case 1:  in = w1; out = o1; break;
        case 2:  in = w2; out = o2; break;
        default: in = w3; out = o3; break;
    }
    float4 v = reinterpret_cast<const float4*>(in)[i];
    ushort4 o;
    o.x = f2bf(v.x); o.y = f2bf(v.y); o.z = f2bf(v.z); o.w = f2bf(v.w);
    reinterpret_cast<ushort4*>(out)[i] = o;
}

#define GLDS(g, s) __builtin_amdgcn_global_load_lds((const __attribute__((address_space(1))) void*)(g), \
                       (__attribute__((address_space(3))) void*)(s), 16, 0, 0)

// ---------------- fused QKV GEMM (2-phase double-buffered staging) ----------------
// grid (24, 64): blockIdx.x = seg(0..2)*8 + n-tile; seg 0->Q, 1->K, 2->V.
// Q/K epilogue: fragment-ready [bh][strip32][s=4][hi=2][l31=32][j=8] (Q pre-scaled).
// V epilogue: fragment-ready V^T [bh][kvt32][ks*2+hi][d=64][j=8] (swapped mfma -> C^T).
__global__ __launch_bounds__(256) void gemm_qkv(const unsigned short* __restrict__ A,
                                                const unsigned short* __restrict__ wqb,
                                                const unsigned short* __restrict__ wkb,
                                                const unsigned short* __restrict__ wvb,
                                                const float* __restrict__ bq,
                                                const float* __restrict__ bk,
                                                const float* __restrict__ bv,
                                                unsigned short* __restrict__ qB,
                                                unsigned short* __restrict__ kB,
                                                unsigned short* __restrict__ vtB) {
    __shared__ unsigned short sA0[128*32];
    __shared__ unsigned short sB0[128*32];
    __shared__ unsigned short sA1[128*32];
    __shared__ unsigned short sB1[128*32];
    const int tid = threadIdx.x;
    const int w  = tid >> 6, l = tid & 63;
    const int lg = l >> 4,  lr = l & 15;
    const int nb  = blockIdx.x;
    const int seg = nb >> 3;
    const int mBase = blockIdx.y * 128;
    const int nBase = (nb & 7) * 128;
    const unsigned short* Bw = (seg == 0) ? wqb : (seg == 1) ? wkb : wvb;
    const float* bias = (seg == 0) ? bq : (seg == 1) ? bk : bv;
    const int wr = w >> 1, wc = w & 1;
    const int srow = l >> 2;
    const int sk0  = (l & 3) * 8;
    const bool segV = (seg == 2);

    f32x4 acc[4][4] = {};

    auto STAGE = [&](unsigned short* dA, unsigned short* dB, int kb) {
        #pragma unroll
        for (int rr = 0; rr < 2; ++rr) {
            const int chunk = w + rr * 4;                 // wave-uniform
            const unsigned short* ga = A  + (size_t)(mBase + chunk*16 + srow) * EMB + kb + sk0;
            GLDS(ga, &dA[chunk * 512]);
            const unsigned short* gb = Bw + (size_t)(nBase + chunk*16 + srow) * EMB + kb + sk0;
            GLDS(gb, &dB[chunk * 512]);
        }
    };
    auto COMPUTE = [&](const unsigned short* dA, const unsigned short* dB) {
        s16x8 af[4], bf[4];
        #pragma unroll
        for (int mi = 0; mi < 4; ++mi)
            af[mi] = *reinterpret_cast<const s16x8*>(&dA[(wr*64 + mi*16 + lr)*32 + lg*8]);
        #pragma unroll
        for (int ni = 0; ni < 4; ++ni)
            bf[ni] = *reinterpret_cast<const s16x8*>(&dB[(wc*64 + ni*16 + lr)*32 + lg*8]);
        if (segV) {
            #pragma unroll
            for (int mi = 0; mi < 4; ++mi)
                #pragma unroll
                for (int ni = 0; ni < 4; ++ni)
                    acc[ni][mi] = mfma16(bf[ni], af[mi], acc[ni][mi]);  // C^T
        } else {
            #pragma unroll
            for (int mi = 0; mi < 4; ++mi)
                #pragma unroll
                for (int ni = 0; ni < 4; ++ni)
                    acc[mi][ni] = mfma16(af[mi], bf[ni], acc[mi][ni]);
        }
    };

    STAGE(sA0, sB0, 0);
    __syncthreads();
    for (int kb = 0; kb < EMB; kb += 64) {
        STAGE(sA1, sB1, kb + 32);       // prefetch hides under COMPUTE
        COMPUTE(sA0, sB0);
        __syncthreads();                // drains mostly-complete prefetch
        if (kb + 64 < EMB) STAGE(sA0, sB0, kb + 64);
        COMPUTE(sA1, sB1);
        __syncthreads();
    }

    const int colBase = nBase + wc * 64;
    const int rowBase = mBase + wr * 64;
    if (!segV) {
        unsigned short* outp = seg ? kB : qB;
        const float oscale = seg ? 1.0f : QSCALE;
        #pragma unroll
        for (int ni = 0; ni < 4; ++ni) {
            const int col = colBase + ni*16 + lr;
            const float bv = bias[col];
            const int h = col >> 6, d = col & 63;
            const int inner = ((d >> 4) * 2 + ((d >> 3) & 1)) * 256 + (d & 7);
            #pragma unroll
            for (int mi = 0; mi < 4; ++mi) {
                #pragma unroll
                for (int r = 0; r < 4; ++r) {
                    const int gr = rowBase + mi*16 + lg*4 + r;
                    const int b = gr >> 11, sin_ = gr & 2047;
                    const int strip = sin_ >> 5, l31q = sin_ & 31;
                    outp[(size_t)(b*NH + h) * (SEQ*DHEAD) + strip*2048 + inner + l31q*8]
                        = f2bf((acc[mi][ni][r] + bv) * oscale);
                }
            }
        }
    } else {
        unsigned short* outp = vtB;
        #pragma unroll
        for (int ni = 0; ni < 4; ++ni) {
            #pragma unroll
            for (int r = 0; r < 4; ++r) {
                const int n = colBase + ni*16 + lg*4 + r;
                const float bv = bias[n];
                const int h = n >> 6, d = n & 63;
                #pragma unroll
                for (int mi = 0; mi < 4; ++mi) {
                    const int tok = rowBase + mi*16 + lr;
                    const int b = tok >> 11, sv = tok & 2047;
                    const int kvt = sv >> 5, ks = (sv >> 4) & 1, hi2 = (sv >> 3) & 1, j = sv & 7;
                    outp[(size_t)(b*NH + h) * (SEQ*DHEAD) + kvt*2048 + (ks*2 + hi2)*512 + d*8 + j]
                        = f2bf(acc[ni][mi][r] + bv);
                }
            }
        }
    }
}

// ---------------- output projection GEMM (2-phase, fp32 out + bias) ----------------
__global__ __launch_bounds__(256) void gemm_out(const unsigned short* __restrict__ A,
                                                const unsigned short* __restrict__ Bw,
                                                const float* __restrict__ bias,
                                                float* __restrict__ Out) {
    __shared__ unsigned short sA0[128*32];
    __shared__ unsigned short sB0[128*32];
    __shared__ unsigned short sA1[128*32];
    __shared__ unsigned short sB1[128*32];
    const int tid = threadIdx.x;
    const int w  = tid >> 6, l = tid & 63;
    const int lg = l >> 4,  lr = l & 15;
    const int mBase = blockIdx.y * 128;
    const int nBase = blockIdx.x * 128;
    const int wr = w >> 1, wc = w & 1;
    const int srow = l >> 2;
    const int sk0  = (l & 3) * 8;

    f32x4 acc[4][4] = {};

    auto STAGE = [&](unsigned short* dA, unsigned short* dB, int kb) {
        #pragma unroll
        for (int rr = 0; rr < 2; ++rr) {
            const int chunk = w + rr * 4;
            const unsigned short* ga = A  + (size_t)(mBase + chunk*16 + srow) * EMB + kb + sk0;
            GLDS(ga, &dA[chunk * 512]);
            const unsigned short* gb = Bw + (size_t)(nBase + chunk*16 + srow) * EMB + kb + sk0;
            GLDS(gb, &dB[chunk * 512]);
        }
    };
    auto COMPUTE = [&](const unsigned short* dA, const unsigned short* dB) {
        s16x8 af[4], bf[4];
        #pragma unroll
        for (int mi = 0; mi < 4; ++mi)
            af[mi] = *reinterpret_cast<const s16x8*>(&dA[(wr*64 + mi*16 + lr)*32 + lg*8]);
        #pragma unroll
        for (int ni = 0; ni < 4; ++ni)
            bf[ni] = *reinterpret_cast<const s16x8*>(&dB[(wc*64 + ni*16 + lr)*32 + lg*8]);
        #pragma unroll
        for (int mi = 0; mi < 4; ++mi)
            #pragma unroll
            for (int ni = 0; ni < 4; ++ni)
                acc[mi][ni] = mfma16(af[mi], bf[ni], acc[mi][ni]);
    };

    STAGE(sA0, sB0, 0);
    __syncthreads();
    for (int kb = 0; kb < EMB; kb += 64) {
        STAGE(sA1, sB1, kb + 32);
        COMPUTE(sA0, sB0);
        __syncthreads();
        if (kb + 64 < EMB) STAGE(sA0, sB0, kb + 64);
        COMPUTE(sA1, sB1);
        __syncthreads();
    }

    const int colBase = nBase + wc * 64;
    const int rowBase = mBase + wr * 64;
    #pragma unroll
    for (int ni = 0; ni < 4; ++ni) {
        const int col = colBase + ni*16 + lr;
        const float bv = bias[col];
        #pragma unroll
        for (int mi = 0; mi < 4; ++mi) {
            #pragma unroll
            for (int r = 0; r < 4; ++r) {
                const int gr = rowBase + mi*16 + lg*4 + r;
                Out[(size_t)gr * EMB + col] = acc[mi][ni][r] + bv;
            }
        }
    }
}

// ---------------- flash attention (causal), swapped-operand 32x32 MFMA ----------------
// 1 wave per block; 4096 blocks. softmax in exp2 domain (Q pre-scaled by 0.125*log2e).
__global__ __launch_bounds__(64) void attn_fwd(const unsigned short* __restrict__ qb,
                                               const unsigned short* __restrict__ kb,
                                               const unsigned short* __restrict__ vb,
                                               unsigned short* __restrict__ ctx) {
    __shared__ __align__(16) unsigned sld[32*36];
    const int l = threadIdx.x;
    const int l31 = l & 31, hi = l >> 5;
    const int bh = blockIdx.x & 63;
    const int strip = (NSTRIP - 1) - ((int)blockIdx.x >> 6);   // mixes depth across CUs
    const int q0 = strip * 32;
    const size_t hbase = (size_t)bh * SEQ * DHEAD;
    const unsigned short* qh = qb + hbase;
    const unsigned short* kh = kb + hbase;
    const unsigned short* vh = vb + hbase;

    s16x8 qf[4];
    #pragma unroll
    for (int s = 0; s < 4; ++s)
        qf[s] = *reinterpret_cast<const s16x8*>(&qh[strip*2048 + s*512 + l*8]);

    f32x16 o0 = {}, o1 = {};
    float m = -__builtin_inff(), lsum = 0.f;
    const int ntiles = strip + 1;

    s16x8 kfA[4], vfA[4], kfB[4], vfB[4];

    auto LOADKV = [&](s16x8* kf, s16x8* vf, int t) {
        const unsigned short* kp = kh + t*2048;
        #pragma unroll
        for (int s = 0; s < 4; ++s)
            kf[s] = *reinterpret_cast<const s16x8*>(&kp[s*512 + l*8]);
        const unsigned short* vp = vh + t*2048 + hi*512 + l31*8;
        #pragma unroll
        for (int ks = 0; ks < 2; ++ks) {
            vf[ks]     = *reinterpret_cast<const s16x8*>(&vp[ks*1024]);
            vf[2 + ks] = *reinterpret_cast<const s16x8*>(&vp[ks*1024 + 256]);
        }
    };

    auto BODY = [&](s16x8* kf, s16x8* vf, int t) {
        f32x16 sa = {};
        #pragma unroll
        for (int s = 0; s < 4; ++s) sa = mfma32(kf[s], qf[s], sa);

        if (t == strip) {  // diagonal tile: mask kv > q
            #pragma unroll
            for (int r = 0; r < 16; ++r) {
                const int kvloc = (r & 3) + 8*(r >> 2) + 4*hi;
                if (kvloc > l31) sa[r] = -__builtin_inff();
            }
        }

        // max reduce: 5+2 v_max3 + 1 fmax + 1 shfl
        const float a0 = max3f(sa[0],  sa[1],  sa[2]);
        const float a1 = max3f(sa[3],  sa[4],  sa[5]);
        const float a2 = max3f(sa[6],  sa[7],  sa[8]);
        const float a3 = max3f(sa[9],  sa[10], sa[11]);
        const float a4 = max3f(sa[12], sa[13], sa[14]);
        const float b0 = max3f(a0, a1, a2);
        const float b1 = max3f(a3, a4, sa[15]);
        float pm = fmaxf(b0, b1);
        pm = fmaxf(pm, __shfl_xor(pm, 32));

        float mn = m;
        if (!__all(pm <= m + 8.0f)) {        // T13 defer-max (log2 domain: p <= 256)
            mn = fmaxf(m, pm);
            const float fs = exp2r(m - mn);
            o0 *= fs; o1 *= fs; lsum *= fs;
            m = mn;
        }

        #pragma unroll
        for (int r = 0; r < 16; ++r) sa[r] = exp2r(sa[r] - mn);   // in-place

        // sum tree (explicit temps, no array copies)
        const float s0 = sa[0]+sa[1],   s1 = sa[2]+sa[3],   s2 = sa[4]+sa[5],   s3 = sa[6]+sa[7];
        const float s4 = sa[8]+sa[9],   s5 = sa[10]+sa[11], s6 = sa[12]+sa[13], s7 = sa[14]+sa[15];
        const float t0 = s0+s1, t1 = s2+s3, t2 = s4+s5, t3 = s6+s7;
        float rs = (t0+t1) + (t2+t3);
        rs += __shfl_xor(rs, 32);
        lsum += rs;

        unsigned u[4], v[4];
        #pragma unroll
        for (int r2 = 0; r2 < 4; ++r2) {
            u[r2] = cvtpk(sa[4*r2 + 0], sa[4*r2 + 1]);
            v[r2] = cvtpk(sa[4*r2 + 2], sa[4*r2 + 3]);
        }
        plane_swap(u[0], u[1]); plane_swap(v[0], v[1]);
        plane_swap(u[2], u[3]); plane_swap(v[2], v[3]);
        const s16x8 pf0 = frag4(u[0], v[0], u[1], v[1]);
        const s16x8 pf1 = frag4(u[2], v[2], u[3], v[3]);

        o0 = mfma32(vf[0], pf0, o0);
        o0 = mfma32(vf[1], pf1, o0);
        o1 = mfma32(vf[2], pf0, o1);
        o1 = mfma32(vf[3], pf1, o1);
    };

    LOADKV(kfA, vfA, 0);
    int t = 0;
    for (; t + 1 < ntiles; t += 2) {
        LOADKV(kfB, vfB, t + 1);
        BODY(kfA, vfA, t);
        if (t + 2 < ntiles) LOADKV(kfA, vfA, t + 2);
        BODY(kfB, vfB, t + 1);
    }
    if (t < ntiles) BODY(kfA, vfA, t);

    // ---- epilogue: normalize, wave-local LDS transpose, coalesced store ----
    const float inv = 1.0f / lsum;
    #pragma unroll
    for (int dt = 0; dt < 2; ++dt) {
        #pragma unroll
        for (int r2 = 0; r2 < 4; ++r2) {
            const float e0 = (dt ? o1[4*r2+0] : o0[4*r2+0]) * inv;
            const float e1 = (dt ? o1[4*r2+1] : o0[4*r2+1]) * inv;
            const float e2 = (dt ? o1[4*r2+2] : o0[4*r2+2]) * inv;
            const float e3 = (dt ? o1[4*r2+3] : o0[4*r2+3]) * inv;
            const int col = 4*r2 + 2*hi + 16*dt;
            sld[l31*36 + col]     = cvtpk(e0, e1);
            sld[l31*36 + col + 1] = cvtpk(e2, e3);
        }
    }
    asm volatile("s_waitcnt lgkmcnt(0)" ::: "memory");
    __builtin_amdgcn_sched_barrier(0);
    const int row = l >> 1, half = l & 1;
    const unsigned* rp = &sld[row*36 + half*16];
    const int b = bh >> 4, h = bh & 15;
    unsigned short* op = &ctx[((size_t)b*SEQ + q0 + row) * EMB + h*DHEAD + half*32];
    #pragma unroll
    for (int i = 0; i < 4; ++i) {
        uint4 d4 = *reinterpret_cast<const uint4*>(rp + i*4);
        *reinterpret_cast<uint4*>(op + i*8) = d4;
    }
}

// ---------------- launch ----------------
extern "C" void kernel_launch(void* const* d_in, const int* in_sizes, int n_in,
                              void* d_out, int out_size, void* d_ws, size_t ws_size,
                              hipStream_t stream) {
    const float* x  = (const float*)d_in[0];
    const float* wq = (const float*)d_in[1];
    const float* bq = (const float*)d_in[2];
    const float* wk = (const float*)d_in[3];
    const float* bk = (const float*)d_in[4];
    const float* wv = (const float*)d_in[5];
    const float* bv = (const float*)d_in[6];
    const float* wo = (const float*)d_in[7];
    const float* bo = (const float*)d_in[8];
    float* out = (float*)d_out;

    char* ws = (char*)d_ws;
    const size_t MB = 1ull << 20;
    unsigned short* xb  = (unsigned short*)(ws);            // 16 MB; reused as ctx later
    unsigned short* wqb = (unsigned short*)(ws + 16*MB);
    unsigned short* wkb = (unsigned short*)(ws + 18*MB);
    unsigned short* wvb = (unsigned short*)(ws + 20*MB);
    unsigned short* wob = (unsigned short*)(ws + 22*MB);
    unsigned short* qB  = (unsigned short*)(ws + 24*MB);    // fragment-ready, pre-scaled (exp2 domain)
    unsigned short* kB  = (unsigned short*)(ws + 40*MB);    // fragment-ready
    unsigned short* vtB = (unsigned short*)(ws + 56*MB);    // fragment-ready V^T
    unsigned short* ctx = xb;

    const int nx4 = MROWS * EMB / 4;
    const int nw4 = EMB * EMB / 4;
    cvt_bf16<<<(nx4 + 255)/256, 256, 0, stream>>>(x, xb, nx4);
    cvt_bf16_w<<<dim3((nw4 + 255)/256, 4), 256, 0, stream>>>(wq, wk, wv, wo, wqb, wkb, wvb, wob, nw4);

    gemm_qkv<<<dim3(24, MROWS/128), 256, 0, stream>>>(xb, wqb, wkb, wvb, bq, bk, bv, qB, kB, vtB);

    attn_fwd<<<dim3(NSTRIP * BATCH * NH), 64, 0, stream>>>(qB, kB, vtB, ctx);

    gemm_out<<<dim3(EMB/128, MROWS/128), 256, 0, stream>>>(ctx, wob, bo, out);
}